// Round 13
// baseline (54.289 us; speedup 1.0000x reference)
//
#include <hip/hip_runtime.h>
#include <hip/hip_bf16.h>
#include <math.h>

#define NROW 8192
#define DIM  128
#define WT   64                    // per-wave tile (64x64)
#define NTW  (NROW / WT)           // 128
#define NWTILE ((NTW * (NTW + 1)) / 2)   // 8256 wave-tiles
#define NBLK  (NWTILE / 4)         // 2064 blocks x 4 waves

typedef __bf16 bf16x8 __attribute__((ext_vector_type(8)));
typedef float  f32x4  __attribute__((ext_vector_type(4)));

#define G2     369.3299304675746f   /* 256 * log2(e): logits in base-2 */
#define QPOS   (0.9375f * G2)       /* xp = G2*s^2 - 2*G2*s + QPOS      */
#define QNEG   (-0.0625f * G2)      /* xn = G2*t^2 + QNEG, t=max(s,-.25)*/
#define NEGBIG (-3.0e38f)
#define MSENT  (-4000.0f)           /* empty-class sentinel */

// ---- Kernel A: normalize rows -> bf16 ----
__global__ __launch_bounds__(256)
void prep_kernel(const float* __restrict__ f, __hip_bfloat16* __restrict__ fhi) {
    int row  = blockIdx.x * 4 + (threadIdx.x >> 6);
    int lane = threadIdx.x & 63;
    float2 v = ((const float2*)(f + (size_t)row * DIM))[lane];
    float ss = v.x * v.x + v.y * v.y;
    #pragma unroll
    for (int off = 32; off; off >>= 1) ss += __shfl_xor(ss, off, 64);
    float inv = 1.0f / fmaxf(sqrtf(ss), 1e-12f);
    __hip_bfloat162 hv;
    hv.x = __float2bfloat16(v.x * inv);
    hv.y = __float2bfloat16(v.y * inv);
    ((__hip_bfloat162*)(fhi + (size_t)row * DIM))[lane] = hv;
}

// ---- Kernel B: ZERO-BARRIER wave-private sim ----
// Each wave: own 64x64 tile, own 16KB LDS slice, self-paced vmcnt pipeline.
__global__ __launch_bounds__(256, 2)
void sim_kernel(const __hip_bfloat16* __restrict__ fhi,
                const int* __restrict__ lab,
                float4* __restrict__ waveRes) {
    const int tid  = threadIdx.x;
    const int w    = tid >> 6;
    const int lane = tid & 63;
    const int lrow = lane & 15;
    const int lk   = lane >> 4;

    // global wave-tile index -> (tr, tc), tc >= tr, 128x128 grid of 64^2 tiles
    const int g = blockIdx.x * 4 + w;            // 0..8255
    int tr = (int)((257.0f - sqrtf(fmaxf(66049.0f - 8.0f * (float)g, 0.f))) * 0.5f);
    if (tr > 127) tr = 127;
    if (tr < 0) tr = 0;
    while (tr > 0 && g < tr * NTW - (tr * (tr - 1)) / 2) --tr;
    while (g >= (tr + 1) * NTW - ((tr + 1) * tr) / 2) ++tr;
    const int tc = tr + (g - (tr * NTW - (tr * (tr - 1)) / 2));

    const int rowBase = tr * WT;
    const int colBase = tc * WT;
    const bool edge = (tr == tc);

    // wave-private LDS slice: A[64][128B] + B[64][128B] = 16KB
    __shared__ __align__(16) char smem[4 * 16384];
    char* Abase = smem + w * 16384;
    char* Bbase = Abase + 8192;

    const int r8  = lane >> 3;                 // row within 8-row segment
    const int kbs = ((lane & 7) << 4) ^ (r8 << 4);  // pre-swizzled source byte

    // stage one K=64 chunk (c=0/1) of A and B: 16 x 1KB wave-instructions
    auto STAGE = [&](int c) {
        #pragma unroll
        for (int s = 0; s < 8; ++s) {
            int row = s * 8 + r8;
            const char* ga = (const char*)fhi + (size_t)(rowBase + row) * 256
                           + c * 128 + kbs;
            __builtin_amdgcn_global_load_lds(
                (const __attribute__((address_space(1))) void*)ga,
                (__attribute__((address_space(3))) void*)(Abase + s * 1024), 16, 0, 0);
        }
        #pragma unroll
        for (int s = 0; s < 8; ++s) {
            int row = s * 8 + r8;
            const char* gb = (const char*)fhi + (size_t)(colBase + row) * 256
                           + c * 128 + kbs;
            __builtin_amdgcn_global_load_lds(
                (const __attribute__((address_space(1))) void*)gb,
                (__attribute__((address_space(3))) void*)(Bbase + s * 1024), 16, 0, 0);
        }
    };

    f32x4 acc[4][4];
    #pragma unroll
    for (int mi = 0; mi < 4; ++mi)
        #pragma unroll
        for (int ni = 0; ni < 4; ++ni) acc[mi][ni] = (f32x4){0.f, 0.f, 0.f, 0.f};

    auto COMPUTE = [&]() {
        #pragma unroll
        for (int q = 0; q < 2; ++q) {
            const int kb = q * 64 + lk * 16;
            bf16x8 bfr[4];
            #pragma unroll
            for (int ni = 0; ni < 4; ++ni) {
                int rb = ni * 16 + lrow;
                bfr[ni] = *(const bf16x8*)(Bbase + rb * 128 + (kb ^ ((rb & 7) << 4)));
            }
            #pragma unroll
            for (int mi = 0; mi < 4; ++mi) {
                int ra = mi * 16 + lrow;
                bf16x8 afr = *(const bf16x8*)(Abase + ra * 128 + (kb ^ ((ra & 7) << 4)));
                #pragma unroll
                for (int ni = 0; ni < 4; ++ni)
                    acc[mi][ni] = __builtin_amdgcn_mfma_f32_16x16x32_bf16(
                        afr, bfr[ni], acc[mi][ni], 0, 0, 0);
            }
        }
    };

    STAGE(0);
    // labels direct from global (L2-hot 32KB) - issued after stage, covered by vmcnt(0)
    int lbv[4];
    #pragma unroll
    for (int ni = 0; ni < 4; ++ni) lbv[ni] = lab[colBase + ni * 16 + lrow];
    int4 laR[4];
    #pragma unroll
    for (int mi = 0; mi < 4; ++mi)
        laR[mi] = *(const int4*)&lab[rowBase + mi * 16 + lk * 4];

    asm volatile("s_waitcnt vmcnt(0)" ::: "memory");   // chunk0 + labels landed
    COMPUTE();
    asm volatile("s_waitcnt lgkmcnt(0)" ::: "memory"); // frag reads retired
    STAGE(1);
    asm volatile("s_waitcnt vmcnt(0)" ::: "memory");   // chunk1 landed
    COMPUTE();

    // ---- lean monotone epilogue (wave-local, no barrier) ----
    float minp = 1e30f;    // min s over valid positives (xp decreasing in s)
    float mabs = -1.0f;    // max |t| over valid negatives

#define PASS_A(EDGEF)                                                          \
    _Pragma("unroll")                                                          \
    for (int mi = 0; mi < 4; ++mi) {                                           \
        const int la[4] = {laR[mi].x, laR[mi].y, laR[mi].z, laR[mi].w};        \
        _Pragma("unroll")                                                      \
        for (int ni = 0; ni < 4; ++ni) {                                       \
            _Pragma("unroll")                                                  \
            for (int r = 0; r < 4; ++r) {                                      \
                float s = acc[mi][ni][r];                                      \
                bool pos = (la[r] == lbv[ni]);                                 \
                float t = fmaxf(s, -0.25f);                                    \
                bool valid = true;                                             \
                if (EDGEF) {                                                   \
                    int il = mi * 16 + lk * 4 + r;                             \
                    int jl = ni * 16 + lrow;                                   \
                    valid = (jl > il);                                         \
                    pos = pos && valid;                                        \
                }                                                              \
                float u = pos ? s : t;                                         \
                minp = fminf(minp, pos ? s : 1e30f);                           \
                bool nm = EDGEF ? (valid && !pos) : !pos;                      \
                mabs = fmaxf(mabs, nm ? fabsf(t) : -1.0f);                     \
                acc[mi][ni][r] = u;                                            \
            }                                                                  \
        }                                                                      \
    }
    if (edge) { PASS_A(true) } else { PASS_A(false) }
#undef PASS_A

    #pragma unroll
    for (int off = 32; off; off >>= 1) {
        minp = fminf(minp, __shfl_xor(minp, off, 64));
        mabs = fmaxf(mabs, __shfl_xor(mabs, off, 64));
    }
    const float Mp = (minp < 2.0f)
        ? fmaf(G2, minp * minp, fmaf(-2.0f * G2, minp, QPOS)) : MSENT;
    const float Mn = (mabs >= 0.0f) ? fmaf(G2, mabs * mabs, QNEG) : MSENT;
    const float qph = QPOS - Mp;
    const float qnh = QNEG - Mn;
    float sp = 0.f, sn = 0.f;

#define PASS_B(EDGEF)                                                          \
    _Pragma("unroll")                                                          \
    for (int mi = 0; mi < 4; ++mi) {                                           \
        const int la[4] = {laR[mi].x, laR[mi].y, laR[mi].z, laR[mi].w};        \
        _Pragma("unroll")                                                      \
        for (int ni = 0; ni < 4; ++ni) {                                       \
            _Pragma("unroll")                                                  \
            for (int r = 0; r < 4; ++r) {                                      \
                float u = acc[mi][ni][r];                                      \
                bool pos = (la[r] == lbv[ni]);                                 \
                float P  = pos ? (-2.0f * G2) : 0.0f;                          \
                float Qh = pos ? qph : qnh;                                    \
                float e = __builtin_amdgcn_exp2f(                              \
                              fmaf(G2, u * u, fmaf(P, u, Qh)));                \
                if (EDGEF) {                                                   \
                    int il = mi * 16 + lk * 4 + r;                             \
                    int jl = ni * 16 + lrow;                                   \
                    e = (jl > il) ? e : 0.f;                                   \
                }                                                              \
                float ep = pos ? e : 0.f;                                      \
                sp += ep;                                                      \
                sn += (e - ep);                                                \
            }                                                                  \
        }                                                                      \
    }
    if (edge) { PASS_B(true) } else { PASS_B(false) }
#undef PASS_B

    #pragma unroll
    for (int off = 32; off; off >>= 1) {
        sp += __shfl_xor(sp, off, 64);
        sn += __shfl_xor(sn, off, 64);
    }
    if (lane == 0) waveRes[g] = make_float4(Mp, sp, Mn, sn);
}

// ---- Kernel C: single-pass final (two-phase max/sum) + softplus ----
__global__ __launch_bounds__(1024)
void final_kernel(const float4* __restrict__ waveRes, float* __restrict__ out) {
    __shared__ float red[16][4];
    const int tid  = threadIdx.x;
    const int wv   = tid >> 6;
    const int lane = tid & 63;

    float4 e[9];
    int ne = 0;
    for (int i = tid; i < NWTILE; i += 1024) e[ne++] = waveRes[i];

    // phase A: global maxes (independent fmax, fully pipelined)
    float mp = NEGBIG, mn = NEGBIG;
    for (int k = 0; k < ne; ++k) {
        mp = fmaxf(mp, e[k].x);
        mn = fmaxf(mn, e[k].z);
    }
    #pragma unroll
    for (int off = 32; off; off >>= 1) {
        mp = fmaxf(mp, __shfl_xor(mp, off, 64));
        mn = fmaxf(mn, __shfl_xor(mn, off, 64));
    }
    if (lane == 0) { red[wv][0] = mp; red[wv][1] = mn; }
    __syncthreads();
    float MP = red[0][0], MN = red[0][1];
    #pragma unroll
    for (int q = 1; q < 16; ++q) {
        MP = fmaxf(MP, red[q][0]);
        MN = fmaxf(MN, red[q][1]);
    }

    // phase B: rescaled sums (independent exp2 + fma)
    float sp = 0.f, sn = 0.f;
    for (int k = 0; k < ne; ++k) {
        sp = fmaf(e[k].y, __builtin_amdgcn_exp2f(e[k].x - MP), sp);
        sn = fmaf(e[k].w, __builtin_amdgcn_exp2f(e[k].z - MN), sn);
    }
    #pragma unroll
    for (int off = 32; off; off >>= 1) {
        sp += __shfl_xor(sp, off, 64);
        sn += __shfl_xor(sn, off, 64);
    }
    __syncthreads();
    if (lane == 0) { red[wv][2] = sp; red[wv][3] = sn; }
    __syncthreads();
    if (tid == 0) {
        float Sp = 0.f, Sn = 0.f;
        #pragma unroll
        for (int q = 0; q < 16; ++q) { Sp += red[q][2]; Sn += red[q][3]; }
        const double LN2 = 0.6931471805599453;
        double lse_p = ((double)MP + log2((double)Sp)) * LN2;
        double lse_n = ((double)MN + log2((double)Sn)) * LN2;
        double xx = lse_p + lse_n;
        double r = (xx > 30.0) ? xx : log1p(exp(xx));
        out[0] = (float)r;
    }
}

extern "C" void kernel_launch(void* const* d_in, const int* in_sizes, int n_in,
                              void* d_out, int out_size, void* d_ws, size_t ws_size,
                              hipStream_t stream) {
    const float* f   = (const float*)d_in[0];
    const int*   lab = (const int*)d_in[1];
    float*  out      = (float*)d_out;

    __hip_bfloat16* fhi = (__hip_bfloat16*)d_ws;                   // 2 MB
    float4* waveRes = (float4*)((char*)d_ws + 4u * 1024 * 1024);   // 8256 float4

    prep_kernel<<<NROW / 4, 256, 0, stream>>>(f, fhi);
    sim_kernel<<<NBLK, 256, 0, stream>>>(fhi, lab, waveRes);
    final_kernel<<<1, 1024, 0, stream>>>(waveRes, out);
}